// Round 2
// baseline (494.338 us; speedup 1.0000x reference)
//
#include <hip/hip_runtime.h>

// Problem constants (from reference setup_inputs)
constexpr int B = 2, C = 16, D = 80, H = 96, W = 96;
constexpr int S  = D * H * W;        // 737280 spatial per batch
constexpr int N  = B * C * S;        // 23592960 elems per tensor
// Padded pooled layout: halo of 3 on d/h; w gets 4 left (alignment) + 12 right
constexpr int DP = D + 6;            // 86
constexpr int HP = H + 6;            // 102
constexpr int WP = 112;              // 4 + 96 + 12, multiple of 4 for float4 rows
constexpr int PP = DP * HP * WP;     // 982464 per channel per batch

// Workspace float offsets: 4 padded pooled arrays [t*2+c][b][dp][hp][wp]
// order: FMAX, FAVG, MMAX, MAVG  -> offset (t*2+c)*B*PP
// Total ws need: 4*B*PP*4 bytes = 31,438,848 bytes. Gates live in registers.

__device__ __forceinline__ float sigmoidf_(float x) {
    return 1.0f / (1.0f + __expf(-x));
}

// ---------------------------------------------------------------------------
// Kernel 1: channel max/mean pool of fix and move into zero-padded planar
// layout. One thread per PADDED float4 slot; halo lanes write zeros (no
// separate memset dispatch). Interior lanes (75%) do the 16-channel pool.
// ---------------------------------------------------------------------------
__global__ __launch_bounds__(256) void pool_pad_kernel(
    const float* __restrict__ fix, const float* __restrict__ mov,
    float* __restrict__ ws)
{
    int i = blockIdx.x * 256 + threadIdx.x;        // over B*PP/4 padded float4s
    if (i >= B * PP / 4) return;

    int wp4 = i % (WP / 4);                         // 0..27
    int t   = i / (WP / 4);
    int hp  = t % HP;  t /= HP;
    int dp  = t % DP;
    int b   = t / DP;

    float4* ws4 = (float4*)ws;
    bool interior = (dp >= 3) & (dp < 3 + D) & (hp >= 3) & (hp < 3 + H)
                  & (wp4 >= 1) & (wp4 < 25);

    if (!interior) {
        float4 z = make_float4(0.f, 0.f, 0.f, 0.f);
        ws4[0 * (B * PP / 4) + i] = z;
        ws4[1 * (B * PP / 4) + i] = z;
        ws4[2 * (B * PP / 4) + i] = z;
        ws4[3 * (B * PP / 4) + i] = z;
        return;
    }

    int d = dp - 3, h = hp - 3, w4 = wp4 - 1;
    const float4* f4 = (const float4*)fix;
    const float4* m4 = (const float4*)mov;
    int base = (b * C * S + (d * H + h) * W) / 4 + w4;   // channel 0 slot
    constexpr int cs = S / 4;                            // channel stride (f4)

    float4 v = f4[base];
    float4 fmx = v, fsm = v;
    #pragma unroll
    for (int c = 1; c < C; c++) {
        v = f4[base + c * cs];
        fmx.x = fmaxf(fmx.x, v.x); fmx.y = fmaxf(fmx.y, v.y);
        fmx.z = fmaxf(fmx.z, v.z); fmx.w = fmaxf(fmx.w, v.w);
        fsm.x += v.x; fsm.y += v.y; fsm.z += v.z; fsm.w += v.w;
    }
    v = m4[base];
    float4 mmx = v, msm = v;
    #pragma unroll
    for (int c = 1; c < C; c++) {
        v = m4[base + c * cs];
        mmx.x = fmaxf(mmx.x, v.x); mmx.y = fmaxf(mmx.y, v.y);
        mmx.z = fmaxf(mmx.z, v.z); mmx.w = fmaxf(mmx.w, v.w);
        msm.x += v.x; msm.y += v.y; msm.z += v.z; msm.w += v.w;
    }
    constexpr float inv = 1.0f / C;
    ws4[0 * (B * PP / 4) + i] = fmx;
    ws4[1 * (B * PP / 4) + i] = make_float4(fsm.x*inv, fsm.y*inv, fsm.z*inv, fsm.w*inv);
    ws4[2 * (B * PP / 4) + i] = mmx;
    ws4[3 * (B * PP / 4) + i] = make_float4(msm.x*inv, msm.y*inv, msm.z*inv, msm.w*inv);
}

// ---------------------------------------------------------------------------
// Kernel 2: fused 7x7x7 conv (both gate tensors) + sigmoid + cross-apply.
// Block (8,8,2) = 128 threads; tile 32x32 (h,w) x 2 (d). Each thread holds a
// 4x4 output tile for BOTH gates in registers (g[2][4][4]), then streams all
// 16 channels of fix/move applying the gates. Gates never touch memory.
// Grid (3,3,80): z = b*40 + dblk.
// ---------------------------------------------------------------------------
__global__ __launch_bounds__(128) void conv_apply_kernel(
    const float* __restrict__ ws_in,
    const float* __restrict__ w_f2m, const float* __restrict__ w_m2f,
    const float* __restrict__ fix, const float* __restrict__ mov,
    float* __restrict__ out)
{
    __shared__ float wsm[2 * 686];
    int tid = threadIdx.x + threadIdx.y * 8 + threadIdx.z * 64;
    for (int j = tid; j < 686; j += 128) {
        wsm[j]       = w_f2m[j];
        wsm[686 + j] = w_m2f[j];
    }
    __syncthreads();

    int b    = blockIdx.z / (D / 2);
    int dblk = blockIdx.z % (D / 2);
    int d  = dblk * 2 + threadIdx.z;
    int hb = blockIdx.y * 32 + threadIdx.y * 4;
    int wb = blockIdx.x * 32 + threadIdx.x * 4;

    float g[2][4][4];
    #pragma unroll
    for (int tt = 0; tt < 2; tt++)
        #pragma unroll
        for (int oh = 0; oh < 4; oh++)
            #pragma unroll
            for (int ow = 0; ow < 4; ow++) g[tt][oh][ow] = 0.0f;

    // ---- conv phase: tensor 0 = fix gate (FMAX/FAVG, w_f2m), 1 = move gate
    #pragma unroll
    for (int tt = 0; tt < 2; tt++) {
        #pragma unroll 1
        for (int c = 0; c < 2; c++) {
            const float* src = ws_in + (size_t)(tt * 2 + c) * (B * PP) + b * PP;
            #pragma unroll 1
            for (int kd = 0; kd < 7; kd++) {
                const float* plane = src + (d + kd) * (HP * WP);
                float wt[49];
                #pragma unroll
                for (int j = 0; j < 49; j++)
                    wt[j] = wsm[tt * 686 + (c * 7 + kd) * 49 + j];

                #pragma unroll
                for (int r = 0; r < 10; r++) {
                    const float4* rp = (const float4*)(plane + (hb + r) * WP + wb);
                    float4 a0 = rp[0], a1 = rp[1], a2 = rp[2];
                    float row[12];
                    row[0] = a0.x; row[1]  = a0.y; row[2]  = a0.z; row[3]  = a0.w;
                    row[4] = a1.x; row[5]  = a1.y; row[6]  = a1.z; row[7]  = a1.w;
                    row[8] = a2.x; row[9]  = a2.y; row[10] = a2.z; row[11] = a2.w;
                    #pragma unroll
                    for (int oh = 0; oh < 4; oh++) {
                        int kh = r - oh;
                        if (kh >= 0 && kh < 7) {      // compile-time after unroll
                            #pragma unroll
                            for (int kw = 0; kw < 7; kw++) {
                                float wv = wt[kh * 7 + kw];
                                #pragma unroll
                                for (int ow = 0; ow < 4; ow++)
                                    g[tt][oh][ow] = fmaf(row[ow + kw + 1], wv, g[tt][oh][ow]);
                            }
                        }
                    }
                }
            }
        }
    }

    // ---- sigmoid
    #pragma unroll
    for (int tt = 0; tt < 2; tt++)
        #pragma unroll
        for (int oh = 0; oh < 4; oh++)
            #pragma unroll
            for (int ow = 0; ow < 4; ow++)
                g[tt][oh][ow] = sigmoidf_(g[tt][oh][ow]);

    // ---- apply phase: stream all 16 channels
    const float4* f4 = (const float4*)fix;
    const float4* m4 = (const float4*)mov;
    float4*       o4 = (float4*)out;
    constexpr int hw4 = H * W / 4;

    #pragma unroll 1
    for (int c = 0; c < C; c++) {
        int idx = ((b * C + c) * D + d) * hw4 + hb * (W / 4) + (wb >> 2);
        #pragma unroll
        for (int oh = 0; oh < 4; oh++) {
            int ix = idx + oh * (W / 4);
            float4 f = f4[ix], m = m4[ix];
            float4 of, om;
            of.x = fmaf(m.x, g[0][oh][0], f.x);
            of.y = fmaf(m.y, g[0][oh][1], f.y);
            of.z = fmaf(m.z, g[0][oh][2], f.z);
            of.w = fmaf(m.w, g[0][oh][3], f.w);
            om.x = fmaf(f.x, g[1][oh][0], m.x);
            om.y = fmaf(f.y, g[1][oh][1], m.y);
            om.z = fmaf(f.z, g[1][oh][2], m.z);
            om.w = fmaf(f.w, g[1][oh][3], m.w);
            o4[ix]         = of;
            o4[ix + N / 4] = om;
        }
    }
}

extern "C" void kernel_launch(void* const* d_in, const int* in_sizes, int n_in,
                              void* d_out, int out_size, void* d_ws, size_t ws_size,
                              hipStream_t stream)
{
    const float* fix = (const float*)d_in[0];
    const float* mov = (const float*)d_in[1];
    const float* wf  = (const float*)d_in[2];   // w_f2m: gate from fix
    const float* wm  = (const float*)d_in[3];   // w_m2f: gate from move
    float* ws  = (float*)d_ws;
    float* out = (float*)d_out;

    int pool_blocks = (B * PP / 4 + 255) / 256;   // 1919
    pool_pad_kernel<<<pool_blocks, 256, 0, stream>>>(fix, mov, ws);

    dim3 cb(8, 8, 2), cg(3, 3, B * (D / 2));
    conv_apply_kernel<<<cg, cb, 0, stream>>>(ws, wf, wm, fix, mov, out);
}

// Round 3
// 442.910 us; speedup vs baseline: 1.1161x; 1.1161x over previous
//
#include <hip/hip_runtime.h>

// Problem constants (from reference setup_inputs)
constexpr int B = 2, C = 16, D = 80, H = 96, W = 96;
constexpr int S  = D * H * W;        // 737280 spatial per batch
constexpr int N  = B * C * S;        // 23592960 elems per tensor
// Padded pooled layout: halo of 3 on d/h; w gets 4 left (alignment) + 12 right
constexpr int DP = D + 6;            // 86
constexpr int HP = H + 6;            // 102
constexpr int WP = 112;              // 4 + 96 + 12, multiple of 4 for float4 rows
constexpr int PP = DP * HP * WP;     // 982464 per channel per batch

// Workspace float offsets (all multiples of 4 -> float4 aligned)
constexpr int OFF_FMAX = 0;
constexpr int OFF_FAVG = B * PP;
constexpr int OFF_MMAX = 2 * B * PP;
constexpr int OFF_MAVG = 3 * B * PP;
constexpr int OFF_GF   = 4 * B * PP;
constexpr int OFF_GM   = OFF_GF + B * S;
// Total ws need: (OFF_GM + B*S)*4 = 43,235,328 bytes

__device__ __forceinline__ float sigmoidf_(float x) {
    return 1.0f / (1.0f + __expf(-x));
}

// ---------------------------------------------------------------------------
// Kernel 1: channel max/mean pool of fix and move into zero-padded planar
// layout. One thread per PADDED float4 slot; halo lanes write zeros (no
// separate memset dispatch). Interior lanes (75%) do the 16-channel pool.
// 1919 blocks x 256 -> 5.6 waves/SIMD: enough MLP for streaming.
// ---------------------------------------------------------------------------
__global__ __launch_bounds__(256) void pool_pad_kernel(
    const float* __restrict__ fix, const float* __restrict__ mov,
    float* __restrict__ ws)
{
    int i = blockIdx.x * 256 + threadIdx.x;        // over B*PP/4 padded float4s
    if (i >= B * PP / 4) return;

    int wp4 = i % (WP / 4);                         // 0..27
    int t   = i / (WP / 4);
    int hp  = t % HP;  t /= HP;
    int dp  = t % DP;
    int b   = t / DP;

    float4* ws4 = (float4*)ws;
    bool interior = (dp >= 3) & (dp < 3 + D) & (hp >= 3) & (hp < 3 + H)
                  & (wp4 >= 1) & (wp4 < 25);

    if (!interior) {
        float4 z = make_float4(0.f, 0.f, 0.f, 0.f);
        ws4[0 * (B * PP / 4) + i] = z;
        ws4[1 * (B * PP / 4) + i] = z;
        ws4[2 * (B * PP / 4) + i] = z;
        ws4[3 * (B * PP / 4) + i] = z;
        return;
    }

    int d = dp - 3, h = hp - 3, w4 = wp4 - 1;
    const float4* f4 = (const float4*)fix;
    const float4* m4 = (const float4*)mov;
    int base = (b * C * S + (d * H + h) * W) / 4 + w4;   // channel 0 slot
    constexpr int cs = S / 4;                            // channel stride (f4)

    float4 v = f4[base];
    float4 fmx = v, fsm = v;
    #pragma unroll
    for (int c = 1; c < C; c++) {
        v = f4[base + c * cs];
        fmx.x = fmaxf(fmx.x, v.x); fmx.y = fmaxf(fmx.y, v.y);
        fmx.z = fmaxf(fmx.z, v.z); fmx.w = fmaxf(fmx.w, v.w);
        fsm.x += v.x; fsm.y += v.y; fsm.z += v.z; fsm.w += v.w;
    }
    v = m4[base];
    float4 mmx = v, msm = v;
    #pragma unroll
    for (int c = 1; c < C; c++) {
        v = m4[base + c * cs];
        mmx.x = fmaxf(mmx.x, v.x); mmx.y = fmaxf(mmx.y, v.y);
        mmx.z = fmaxf(mmx.z, v.z); mmx.w = fmaxf(mmx.w, v.w);
        msm.x += v.x; msm.y += v.y; msm.z += v.z; msm.w += v.w;
    }
    constexpr float inv = 1.0f / C;
    ws4[0 * (B * PP / 4) + i] = fmx;
    ws4[1 * (B * PP / 4) + i] = make_float4(fsm.x*inv, fsm.y*inv, fsm.z*inv, fsm.w*inv);
    ws4[2 * (B * PP / 4) + i] = mmx;
    ws4[3 * (B * PP / 4) + i] = make_float4(msm.x*inv, msm.y*inv, msm.z*inv, msm.w*inv);
}

// ---------------------------------------------------------------------------
// Kernel 2: 7x7x7 conv over the 2 pooled channels + sigmoid -> gate arrays.
// Block (8,8,4) = 256 thr: 4x4 (h,w) register tile per thread at one d.
// Grid (3,3,80): z = tensor*40 + b*20 + dblk -> 2880 waves (2.8/SIMD), but
// the inner loop is 784 FMAs per 30 L2 loads -> compute-dominated.
// Weights read DIRECTLY from global with wave-uniform indices -> compiler
// scalarizes to s_load; FMAs take the weight as the SGPR operand (no LDS).
// ---------------------------------------------------------------------------
__global__ __launch_bounds__(256) void conv_gate_kernel(
    const float* __restrict__ ws_in,
    const float* __restrict__ w_f2m, const float* __restrict__ w_m2f,
    float* __restrict__ ws_out)
{
    int z      = blockIdx.z;
    int tensor = z / (B * (D / 4));      // 0 = fix gate, 1 = move gate
    int zz     = z % (B * (D / 4));
    int b      = zz / (D / 4);
    int dblk   = zz % (D / 4);

    const float* wsrc = tensor ? w_m2f : w_f2m;
    const float* pmax = ws_in + (tensor ? OFF_MMAX : OFF_FMAX) + b * PP;
    const float* pavg = ws_in + (tensor ? OFF_MAVG : OFF_FAVG) + b * PP;
    float*       gate = ws_out + (tensor ? OFF_GM : OFF_GF) + b * S;

    int d  = dblk * 4 + threadIdx.z;
    int hb = blockIdx.y * 32 + threadIdx.y * 4;
    int wb = blockIdx.x * 32 + threadIdx.x * 4;

    float acc[4][4];
    #pragma unroll
    for (int oh = 0; oh < 4; oh++)
        #pragma unroll
        for (int ow = 0; ow < 4; ow++) acc[oh][ow] = 0.0f;

    #pragma unroll 1
    for (int c = 0; c < 2; c++) {
        const float* src = c ? pavg : pmax;
        #pragma unroll 1
        for (int kd = 0; kd < 7; kd++) {
            const float* plane = src + (d + kd) * (HP * WP);
            float wt[49];                       // wave-uniform -> SGPRs
            #pragma unroll
            for (int j = 0; j < 49; j++) wt[j] = wsrc[(c * 7 + kd) * 49 + j];

            #pragma unroll
            for (int r = 0; r < 10; r++) {
                const float4* rp = (const float4*)(plane + (hb + r) * WP + wb);
                float4 a0 = rp[0], a1 = rp[1], a2 = rp[2];
                float row[12];
                row[0] = a0.x; row[1]  = a0.y; row[2]  = a0.z; row[3]  = a0.w;
                row[4] = a1.x; row[5]  = a1.y; row[6]  = a1.z; row[7]  = a1.w;
                row[8] = a2.x; row[9]  = a2.y; row[10] = a2.z; row[11] = a2.w;
                // padded row hb+r serves output rows oh with kh = r-oh in [0,7)
                #pragma unroll
                for (int oh = 0; oh < 4; oh++) {
                    int kh = r - oh;
                    if (kh >= 0 && kh < 7) {        // compile-time after unroll
                        #pragma unroll
                        for (int kw = 0; kw < 7; kw++) {
                            float wv = wt[kh * 7 + kw];
                            #pragma unroll
                            for (int ow = 0; ow < 4; ow++)
                                acc[oh][ow] = fmaf(row[ow + kw + 1], wv, acc[oh][ow]);
                        }
                    }
                }
            }
        }
    }

    #pragma unroll
    for (int oh = 0; oh < 4; oh++) {
        float4 o;
        o.x = sigmoidf_(acc[oh][0]);
        o.y = sigmoidf_(acc[oh][1]);
        o.z = sigmoidf_(acc[oh][2]);
        o.w = sigmoidf_(acc[oh][3]);
        *(float4*)(gate + (d * H + hb + oh) * W + wb) = o;
    }
}

// ---------------------------------------------------------------------------
// Kernel 3: elementwise cross-apply, full-occupancy streaming.
// fix_out = move*g_fix + fix ; move_out = fix*g_move + move.
// One thread per float4 of one tensor; writes both outputs. 23040 blocks.
// ---------------------------------------------------------------------------
__global__ __launch_bounds__(256) void apply_kernel(
    const float* __restrict__ fix, const float* __restrict__ mov,
    const float* __restrict__ ws, float* __restrict__ out)
{
    int i  = blockIdx.x * 256 + threadIdx.x;   // over N/4
    int w4 = i % (W / 4);
    int t  = i / (W / 4);
    int h  = t % H;  t /= H;
    int d  = t % D;  t /= D;
    int b  = t / C;                            // t = b*C + c

    const float4* f4  = (const float4*)fix;
    const float4* m4  = (const float4*)mov;
    const float4* gf4 = (const float4*)(ws + OFF_GF);
    const float4* gm4 = (const float4*)(ws + OFF_GM);
    float4*       o4  = (float4*)out;

    int sp = ((b * D + d) * H + h) * (W / 4) + w4;
    float4 f = f4[i], m = m4[i], gf = gf4[sp], gm = gm4[sp];

    float4 of, om;
    of.x = fmaf(m.x, gf.x, f.x); of.y = fmaf(m.y, gf.y, f.y);
    of.z = fmaf(m.z, gf.z, f.z); of.w = fmaf(m.w, gf.w, f.w);
    om.x = fmaf(f.x, gm.x, m.x); om.y = fmaf(f.y, gm.y, m.y);
    om.z = fmaf(f.z, gm.z, m.z); om.w = fmaf(f.w, gm.w, m.w);

    o4[i]         = of;
    o4[i + N / 4] = om;
}

extern "C" void kernel_launch(void* const* d_in, const int* in_sizes, int n_in,
                              void* d_out, int out_size, void* d_ws, size_t ws_size,
                              hipStream_t stream)
{
    const float* fix = (const float*)d_in[0];
    const float* mov = (const float*)d_in[1];
    const float* wf  = (const float*)d_in[2];   // w_f2m: gate from fix
    const float* wm  = (const float*)d_in[3];   // w_m2f: gate from move
    float* ws  = (float*)d_ws;
    float* out = (float*)d_out;

    int pool_blocks = (B * PP / 4 + 255) / 256;   // 1919
    pool_pad_kernel<<<pool_blocks, 256, 0, stream>>>(fix, mov, ws);

    dim3 cb(8, 8, 4), cg(3, 3, 2 * B * (D / 4));
    conv_gate_kernel<<<cg, cb, 0, stream>>>(ws, wf, wm, ws);

    apply_kernel<<<(N / 4) / 256, 256, 0, stream>>>(fix, mov, ws, out);
}